// Round 9
// baseline (344.661 us; speedup 1.0000x reference)
//
#include <hip/hip_runtime.h>
#include <math.h>

#define BB 8
#define NQ 2048
#define NK 2048
#define DD 64
#define VV 128
#define EPSF 1e-7f
#define NT3 (NK / 64)   // 32 k-tiles
#define FIXROWS 1024    // fallback only: W[b=0, rows<FIXROWS] scratch, k4 rewrites

typedef _Float16 half_t;
typedef half_t half4 __attribute__((ext_vector_type(4)));
typedef half_t half8 __attribute__((ext_vector_type(8)));
typedef float  floatx4 __attribute__((ext_vector_type(4)));

// exp(-arccosh(1+tt)^2); tt from fp32 norms + fp16-MFMA cross term.
// arccosh(1+tt) = ln(1+u), u = tt + sqrt(tt*(tt+2)).  [round-8 proven]
__device__ __forceinline__ float score_exp(float x2, float y2, float xy)
{
    float sq = fmaf(-2.f, xy, x2 + y2);
    float dn = fmaxf((1.f - x2) * (1.f - y2), EPSF);
    float tt = fmaxf(2.f * sq * __builtin_amdgcn_rcpf(dn), EPSF);
    float u  = tt + __builtin_amdgcn_sqrtf(fmaf(tt, tt, tt + tt));
    float L  = __log2f(1.f + u);
    return __builtin_amdgcn_exp2f(-0.6931471805599453f * L * L);
}

__device__ __forceinline__ half8 cvt8(float4 a, float4 b)
{
    half8 h;
    h[0] = (half_t)a.x; h[1] = (half_t)a.y; h[2] = (half_t)a.z; h[3] = (half_t)a.w;
    h[4] = (half_t)b.x; h[5] = (half_t)b.y; h[6] = (half_t)b.z; h[7] = (half_t)b.w;
    return h;
}

// frag-major global layouts (half8 units) == MFMA lane layout (round-6 proven)
__device__ __forceinline__ size_t khg_idx(int b, int tile, int f, int l)
{ return (((size_t)b * NT3 + tile) * 8 + f) * 64 + l; }
__device__ __forceinline__ size_t vhg_idx(int b, int tile, int f, int l)
{ return (((size_t)b * NT3 + tile) * 16 + f) * 64 + l; }

// fp16 score-bounce LDS: [32][64] halfs, XOR-swizzled (round-6 proven)
__device__ __forceinline__ int ssh_byte(int row, int col)
{
    return ((row << 7) + (col << 1)) ^ ((row & 7) << 4);
}

// ---------------------------------------------------------------------------
// K0: one-time prep. fp16 K-frags (2MB) + V-frags (4MB) frag-major + y2/x2
// row norms (+ b=0 mirrors for the fallback k4). Grid (NK/64, BB).
// [round-8 proven verbatim]
// ---------------------------------------------------------------------------
__global__ __launch_bounds__(256)
void k0_prep(const float* __restrict__ Q, const float* __restrict__ Kp,
             const float* __restrict__ V, half8* __restrict__ Khg,
             half8* __restrict__ Vhg, float* __restrict__ y2g,
             float* __restrict__ x2g, float* __restrict__ wsY,
             float* __restrict__ wsX)
{
    __shared__ float sVt[64 * VV];       // 32 KB fp32 V tile

    const int t = threadIdx.x, b = blockIdx.y, tile = blockIdx.x;
    const int kt = tile * 64;
    const float* Kb = Kp + (size_t)b * NK * DD;
    const float* Qb = Q  + (size_t)b * NQ * DD;
    const float* Vb = V  + (size_t)b * NK * VV;

#pragma unroll
    for (int i = 0; i < 8; ++i)
        ((float4*)sVt)[t + i * 256] = ((const float4*)(Vb + (size_t)kt * VV))[t + i * 256];

#pragma unroll
    for (int i = 0; i < 2; ++i) {
        int s = t + i * 256, f = s >> 6, l = s & 63;
        int krow = kt + (f >> 1) * 16 + (l & 15);
        int dcol = (f & 1) * 32 + (l >> 4) * 8;
        const float4* kp = (const float4*)(Kb + (size_t)krow * DD + dcol);
        Khg[khg_idx(b, tile, f, l)] = cvt8(kp[0], kp[1]);
    }
    if (t < 64) {
        const float4* kr = (const float4*)(Kb + (size_t)(kt + t) * DD);
        float s = 0.f;
#pragma unroll
        for (int i = 0; i < 16; ++i) {
            float4 v = kr[i];
            s = fmaf(v.x,v.x,s); s = fmaf(v.y,v.y,s);
            s = fmaf(v.z,v.z,s); s = fmaf(v.w,v.w,s);
        }
        y2g[(size_t)b * NK + kt + t] = s;
        if (b == 0) wsY[kt + t] = s;
    } else if (t < 128) {
        int r = t - 64;
        const float4* qr = (const float4*)(Qb + (size_t)(kt + r) * DD);
        float s = 0.f;
#pragma unroll
        for (int i = 0; i < 16; ++i) {
            float4 v = qr[i];
            s = fmaf(v.x,v.x,s); s = fmaf(v.y,v.y,s);
            s = fmaf(v.z,v.z,s); s = fmaf(v.w,v.w,s);
        }
        x2g[(size_t)b * NQ + kt + r] = s;
        if (b == 0) wsX[kt + r] = s;
    }
    __syncthreads();

#pragma unroll
    for (int i = 0; i < 4; ++i) {
        int s = t + i * 256, f = s >> 6, l = s & 63;
        int krow_l = (f & 1) * 32 + (l >> 4) * 8;
        int vcol   = (f >> 1) * 16 + (l & 15);
        half8 h;
#pragma unroll
        for (int j = 0; j < 8; ++j) h[j] = (half_t)sVt[(krow_l + j) * VV + vcol];
        Vhg[vhg_idx(b, tile, f, l)] = h;
    }
}

// ---------------------------------------------------------------------------
// K_MAIN (templated):
//  READBACK=1 (big d_ws): sweep 1 stores raw E into the W region (plain
//    stores, L3-resident) alongside the rowsum; sweep 2 reads E back
//    (coalesced, block-local rows), scales by rcp(rsum), nt-stores W, and
//    runs PV from the fp16 bounce. No score recompute, no scratch, no k4.
//  READBACK=0 (fallback): byte-exact round-8 behavior (recompute + wskip).
// 512 threads = 8 waves (qh = w&1, kq = w>>1). Grid: 512 blocks XCD-swizzled.
// ---------------------------------------------------------------------------
template<int READBACK>
__global__ __launch_bounds__(512, 4)
void k_main_t(const float* __restrict__ Q, const half8* __restrict__ Khg,
              const half8* __restrict__ Vhg, const float* __restrict__ y2g,
              const float* __restrict__ x2g, float* __restrict__ W,
              float* __restrict__ O, float* __restrict__ RS, int fixrows)
{
    __shared__ half_t sSh[32 * 64];      // 4 KB fp16 scores bounce (swizzled)
    __shared__ float  y2k[NK];           // 8 KB
    __shared__ float  part[4][32];
    __shared__ float  rsumS[32];

    const int t = threadIdx.x, w = t >> 6, lane = t & 63;
    const int n = lane & 15, quad = lane >> 4;
    const int qh = w & 1, kq = w >> 1;   // kq in 0..3

    const int bid = blockIdx.x;
    const int swz = (bid & 7) * 64 + (bid >> 3);
    const int b = swz >> 6, qb = (swz & 63) * 32;
    const bool wskip = (!READBACK) && (b == 0) && (qb < fixrows);

    const float* Qb = Q + (size_t)b * NQ * DD;

    ((float4*)y2k)[t] = ((const float4*)(y2g + (size_t)b * NK))[t];

    half8 af[2];
#pragma unroll
    for (int ds = 0; ds < 2; ++ds) {
        const float4* qp = (const float4*)(Qb + (size_t)(qb + qh*16 + n) * DD + ds*32 + quad*8);
        af[ds] = cvt8(qp[0], qp[1]);
    }
    float x2r[4];
#pragma unroll
    for (int r = 0; r < 4; ++r)
        x2r[r] = x2g[(size_t)b * NQ + qb + qh * 16 + quad * 4 + r];
    __syncthreads();    // y2k ready

    // ============ sweep 1: row sums (+ E store if READBACK) =================
    float* WbE = W + (size_t)b * NQ * NK + (size_t)qb * NK;
    float srow[4] = {0.f, 0.f, 0.f, 0.f};

    half8 bf[8];
#pragma unroll
    for (int f = 0; f < 8; ++f) bf[f] = Khg[khg_idx(b, kq * 8, f, lane)];

#pragma unroll 1
    for (int kt0 = 0; kt0 < 512; kt0 += 64) {
        const bool pf = (kt0 + 64) < 512;
        half8 bfn[8];
        if (pf) {
#pragma unroll
            for (int f = 0; f < 8; ++f)
                bfn[f] = Khg[khg_idx(b, kq * 8 + ((kt0 + 64) >> 6), f, lane)];
        }

        floatx4 acc4[4] = {};
#pragma unroll
        for (int nt = 0; nt < 4; ++nt)
#pragma unroll
            for (int ds = 0; ds < 2; ++ds)
                acc4[nt] = __builtin_amdgcn_mfma_f32_16x16x32_f16(
                    af[ds], bf[nt * 2 + ds], acc4[nt], 0, 0, 0);

#pragma unroll
        for (int nt = 0; nt < 4; ++nt) {
            int lcol = kq * 512 + kt0 + nt * 16 + n;
            float y2 = y2k[lcol];
#pragma unroll
            for (int r = 0; r < 4; ++r) {
                float e = score_exp(x2r[r], y2, acc4[nt][r]);
                srow[r] += e;
                if (READBACK)   // raw E -> W region (plain store: stay in L3)
                    WbE[(size_t)(qh * 16 + quad * 4 + r) * NK + lcol] = e;
            }
        }
        if (pf) {
#pragma unroll
            for (int f = 0; f < 8; ++f) bf[f] = bfn[f];
        }
    }
    if (READBACK) __threadfence();   // E visible to all block threads

#pragma unroll
    for (int off = 1; off < 16; off <<= 1)
#pragma unroll
        for (int r = 0; r < 4; ++r) srow[r] += __shfl_xor(srow[r], off);
    if (n == 0)
#pragma unroll
        for (int r = 0; r < 4; ++r) part[kq][qh * 16 + quad * 4 + r] = srow[r];
    __syncthreads();
    if (t < 32) {
        float s = (part[0][t] + part[1][t]) + (part[2][t] + part[3][t]);
        RS[(size_t)b * NQ + qb + t] = s;
        rsumS[t] = s;
    }
    __syncthreads();

    floatx4 acc[2] = {};
    float* Wb = W + (size_t)b * NQ * NK;

    if (READBACK) {
        // ============ sweep 2 (read-back): E -> wv -> W(nt) + sSh -> PV =====
        const int erow = t >> 4, ec4 = (t & 15) * 4;
        const float rl2 = __builtin_amdgcn_rcpf(rsumS[erow]);
        float* Er = Wb + (size_t)(qb + erow) * NK;

#pragma unroll 1
        for (int tt = 0; tt < NT3; ++tt) {
            half8 vf[4];
            vf[0] = Vhg[vhg_idx(b, tt, kq * 2,           lane)];
            vf[1] = Vhg[vhg_idx(b, tt, kq * 2 + 1,       lane)];
            vf[2] = Vhg[vhg_idx(b, tt, (kq + 4) * 2,     lane)];
            vf[3] = Vhg[vhg_idx(b, tt, (kq + 4) * 2 + 1, lane)];

            floatx4 e4 = *(const floatx4*)(Er + tt * 64 + ec4);
            floatx4 wv4;
            wv4[0] = e4[0] * rl2; wv4[1] = e4[1] * rl2;
            wv4[2] = e4[2] * rl2; wv4[3] = e4[3] * rl2;
            __builtin_nontemporal_store(wv4, (floatx4*)(Er + tt * 64 + ec4));
            half4 h;
            h[0] = (half_t)wv4[0]; h[1] = (half_t)wv4[1];
            h[2] = (half_t)wv4[2]; h[3] = (half_t)wv4[3];
            *(half4*)((char*)sSh + ssh_byte(erow, ec4)) = h;
            __syncthreads();   // sSh visible

            const int row2 = qh * 16 + n;
            half8 a0 = *(const half8*)((const char*)sSh + ssh_byte(row2, quad * 8));
            half8 a1 = *(const half8*)((const char*)sSh + ssh_byte(row2, 32 + quad * 8));
            acc[0] = __builtin_amdgcn_mfma_f32_16x16x32_f16(a0, vf[0], acc[0], 0, 0, 0);
            acc[0] = __builtin_amdgcn_mfma_f32_16x16x32_f16(a1, vf[1], acc[0], 0, 0, 0);
            acc[1] = __builtin_amdgcn_mfma_f32_16x16x32_f16(a0, vf[2], acc[1], 0, 0, 0);
            acc[1] = __builtin_amdgcn_mfma_f32_16x16x32_f16(a1, vf[3], acc[1], 0, 0, 0);
            __syncthreads();   // sSh reuse protected
        }
    } else {
        // ============ sweep 2 (fallback): round-8 verbatim ===================
        float rlr[4];
#pragma unroll
        for (int r = 0; r < 4; ++r)
            rlr[r] = __builtin_amdgcn_rcpf(rsumS[qh * 16 + quad * 4 + r]);

        half8 kf[2];
#pragma unroll
        for (int ds = 0; ds < 2; ++ds) kf[ds] = Khg[khg_idx(b, 0, kq * 2 + ds, lane)];

#pragma unroll 1
        for (int tt = 0; tt < NT3; ++tt) {
            const bool pf = (tt + 1) < NT3;

            floatx4 a2 = {};
            a2 = __builtin_amdgcn_mfma_f32_16x16x32_f16(af[0], kf[0], a2, 0, 0, 0);
            a2 = __builtin_amdgcn_mfma_f32_16x16x32_f16(af[1], kf[1], a2, 0, 0, 0);

            half8 vf[4];
            vf[0] = Vhg[vhg_idx(b, tt, kq * 2,           lane)];
            vf[1] = Vhg[vhg_idx(b, tt, kq * 2 + 1,       lane)];
            vf[2] = Vhg[vhg_idx(b, tt, (kq + 4) * 2,     lane)];
            vf[3] = Vhg[vhg_idx(b, tt, (kq + 4) * 2 + 1, lane)];
            half8 kfn[2];
            if (pf) {
#pragma unroll
                for (int ds = 0; ds < 2; ++ds)
                    kfn[ds] = Khg[khg_idx(b, tt + 1, kq * 2 + ds, lane)];
            }

            {
                int col  = kq * 16 + n;
                int gcol = tt * 64 + col;
                float y2 = y2k[gcol];
#pragma unroll
                for (int r = 0; r < 4; ++r) {
                    float e  = score_exp(x2r[r], y2, a2[r]);
                    float wv = e * rlr[r];
                    int row = qh * 16 + quad * 4 + r;
                    if (!wskip)
                        __builtin_nontemporal_store(wv, Wb + (size_t)(qb + row) * NK + gcol);
                    *(half_t*)((char*)sSh + ssh_byte(row, col)) = (half_t)wv;
                }
            }
            __syncthreads();

            const int row2 = qh * 16 + n;
            half8 a0 = *(const half8*)((const char*)sSh + ssh_byte(row2, quad * 8));
            half8 a1 = *(const half8*)((const char*)sSh + ssh_byte(row2, 32 + quad * 8));
            acc[0] = __builtin_amdgcn_mfma_f32_16x16x32_f16(a0, vf[0], acc[0], 0, 0, 0);
            acc[0] = __builtin_amdgcn_mfma_f32_16x16x32_f16(a1, vf[1], acc[0], 0, 0, 0);
            acc[1] = __builtin_amdgcn_mfma_f32_16x16x32_f16(a0, vf[2], acc[1], 0, 0, 0);
            acc[1] = __builtin_amdgcn_mfma_f32_16x16x32_f16(a1, vf[3], acc[1], 0, 0, 0);
            __syncthreads();

            if (pf) { kf[0] = kfn[0]; kf[1] = kfn[1]; }
        }
    }

    // A-frags were pre-normalized -> acc IS the output
    float* Ob = O + (size_t)b * NQ * VV;
#pragma unroll
    for (int ci = 0; ci < 2; ++ci) {
        int c = kq + ci * 4;
#pragma unroll
        for (int r = 0; r < 4; ++r)
            Ob[(size_t)(qb + qh * 16 + quad * 4 + r) * VV + c * 16 + n]
                = acc[ci][r];
    }
}

// ---------------------------------------------------------------------------
// K4 (fallback only): rewrite W[b=0, rows<FIXROWS] after k_main.
// [round-8 proven verbatim]
// ---------------------------------------------------------------------------
__global__ __launch_bounds__(256)
void k4_wfix(const float* __restrict__ Q, const float* __restrict__ Kp,
             const float* __restrict__ RS, const float* __restrict__ wsY,
             const float* __restrict__ wsX, float* __restrict__ W)
{
    __shared__ half8 sB[8 * 64];
    __shared__ float y2k[128];
    __shared__ float x2q[32];

    const int t = threadIdx.x, w = t >> 6, lane = t & 63;
    const int n = lane & 15, quad = lane >> 4;
    const int qh = w & 1, kn = w >> 1;
    const int qb = blockIdx.x * 32;
    const int kz = blockIdx.y * 128;

    if (t < 128) y2k[t] = wsY[kz + t];
    if (t < 32)  x2q[t] = wsX[qb + t];
    __syncthreads();

    half8 af[2];
#pragma unroll
    for (int ds = 0; ds < 2; ++ds) {
        const float4* qp = (const float4*)(Q + (size_t)(qb + qh*16 + n) * DD + ds*32 + quad*8);
        af[ds] = cvt8(qp[0], qp[1]);
    }
    float x2r[4], rlr[4];
#pragma unroll
    for (int r = 0; r < 4; ++r) {
        int row = qb + qh * 16 + quad * 4 + r;
        x2r[r] = x2q[qh * 16 + quad * 4 + r];
        rlr[r] = __builtin_amdgcn_rcpf(RS[row]);
    }

#pragma unroll 1
    for (int kt = 0; kt < 128; kt += 64) {
        __syncthreads();
#pragma unroll
        for (int i = 0; i < 2; ++i) {
            int s = t + i * 256, f = s >> 6, l = s & 63;
            int krow = kz + kt + (f >> 1) * 16 + (l & 15);
            int dcol = (f & 1) * 32 + (l >> 4) * 8;
            const float4* kp = (const float4*)(Kp + (size_t)krow * DD + dcol);
            sB[f * 64 + l] = cvt8(kp[0], kp[1]);
        }
        __syncthreads();

        floatx4 a2[2] = {};
#pragma unroll
        for (int nt = 0; nt < 2; ++nt)
#pragma unroll
            for (int ds = 0; ds < 2; ++ds)
                a2[nt] = __builtin_amdgcn_mfma_f32_16x16x32_f16(
                    af[ds], sB[((kn * 2 + nt) * 2 + ds) * 64 + lane], a2[nt], 0, 0, 0);

#pragma unroll
        for (int nt = 0; nt < 2; ++nt) {
            int col = kn * 32 + nt * 16 + n;
            float y2 = y2k[kt + col];
#pragma unroll
            for (int r = 0; r < 4; ++r) {
                float e = score_exp(x2r[r], y2, a2[nt][r]);
                int row = qh * 16 + quad * 4 + r;
                W[(size_t)(qb + row) * NK + kz + kt + col] = e * rlr[r];
            }
        }
    }
}

// ---------------------------------------------------------------------------
extern "C" void kernel_launch(void* const* d_in, const int* in_sizes, int n_in,
                              void* d_out, int out_size, void* d_ws, size_t ws_size,
                              hipStream_t stream)
{
    const float* Q  = (const float*)d_in[0];
    const float* Kp = (const float*)d_in[1];
    const float* Vp = (const float*)d_in[2];

    float* O     = (float*)d_out;                 // (B, Nq, V)
    float* attnW = O + (size_t)BB * NQ * VV;      // (B, Nq, Nk): E then W

    const size_t nKH = (size_t)BB * NT3 * 8  * 64;   // half8 units
    const size_t nVH = (size_t)BB * NT3 * 16 * 64;
    const size_t need = nKH * sizeof(half8) + nVH * sizeof(half8)
                      + (size_t)(BB * NK + 2 * BB * NQ) * sizeof(float);

    if (ws_size >= need) {
        // ---- big-ws path: everything in d_ws; no carve, no wskip, no k4 ----
        half8* Khg = (half8*)d_ws;
        half8* Vhg = Khg + nKH;
        float* y2g = (float*)(Vhg + nVH);
        float* x2g = y2g + (size_t)BB * NK;
        float* RS  = x2g + (size_t)BB * NQ;

        k0_prep<<<dim3(NK / 64, BB), 256, 0, stream>>>(Q, Kp, Vp, Khg, Vhg,
                                                       y2g, x2g, y2g, x2g);
        k_main_t<1><<<dim3(BB * (NQ / 32)), 512, 0, stream>>>(
            Q, Khg, Vhg, y2g, x2g, attnW, O, RS, 0);
    } else {
        // ---- fallback: byte-exact round-8 path -----------------------------
        half8* Khg = (half8*)attnW;
        half8* Vhg = Khg + nKH;
        float* y2g = (float*)(Vhg + nVH);
        float* x2g = y2g + (size_t)BB * NK;

        float* RS  = (float*)d_ws;                 // B*NQ
        float* wsY = RS  + (size_t)BB * NQ;        // NK (b=0 K norms)
        float* wsX = wsY + NK;                     // NQ (b=0 Q norms)

        k0_prep<<<dim3(NK / 64, BB), 256, 0, stream>>>(Q, Kp, Vp, Khg, Vhg,
                                                       y2g, x2g, wsY, wsX);
        k_main_t<0><<<dim3(BB * (NQ / 32)), 512, 0, stream>>>(
            Q, Khg, Vhg, y2g, x2g, attnW, O, RS, FIXROWS);
        k4_wfix<<<dim3(FIXROWS / 32, 16), 256, 0, stream>>>(Q, Kp, RS, wsY, wsX, attnW);
    }
}

// Round 10
// 204.381 us; speedup vs baseline: 1.6864x; 1.6864x over previous
//
#include <hip/hip_runtime.h>
#include <math.h>

#define BB 8
#define NQ 2048
#define NK 2048
#define DD 64
#define VV 128
#define EPSF 1e-7f
#define NT3 (NK / 64)   // 32 k-tiles

typedef _Float16 half_t;
typedef half_t half8 __attribute__((ext_vector_type(8)));
typedef float  floatx4 __attribute__((ext_vector_type(4)));

// exp(-arccosh(1+tt)^2); tt from fp32 norms + fp16-MFMA cross term.
// arccosh(1+tt) = ln(1+u), u = tt + sqrt(tt*(tt+2)).  [round-8 proven]
__device__ __forceinline__ float score_exp(float x2, float y2, float xy)
{
    float sq = fmaf(-2.f, xy, x2 + y2);
    float dn = fmaxf((1.f - x2) * (1.f - y2), EPSF);
    float tt = fmaxf(2.f * sq * __builtin_amdgcn_rcpf(dn), EPSF);
    float u  = tt + __builtin_amdgcn_sqrtf(fmaf(tt, tt, tt + tt));
    float L  = __log2f(1.f + u);
    return __builtin_amdgcn_exp2f(-0.6931471805599453f * L * L);
}

__device__ __forceinline__ half8 cvt8(float4 a, float4 b)
{
    half8 h;
    h[0] = (half_t)a.x; h[1] = (half_t)a.y; h[2] = (half_t)a.z; h[3] = (half_t)a.w;
    h[4] = (half_t)b.x; h[5] = (half_t)b.y; h[6] = (half_t)b.z; h[7] = (half_t)b.w;
    return h;
}

// frag-major global layouts (half8 units) == MFMA lane layout (round-6 proven)
__device__ __forceinline__ size_t khg_idx(int b, int tile, int f, int l)
{ return (((size_t)b * NT3 + tile) * 8 + f) * 64 + l; }
__device__ __forceinline__ size_t vhg_idx(int b, int tile, int f, int l)
{ return (((size_t)b * NT3 + tile) * 16 + f) * 64 + l; }

// fp16 score-bounce LDS: [32][64] halfs, XOR-swizzled (round-6 proven)
__device__ __forceinline__ int ssh_byte(int row, int col)
{
    return ((row << 7) + (col << 1)) ^ ((row & 7) << 4);
}

// ---------------------------------------------------------------------------
// K0: one-time prep into d_ws (proven big enough in round 9). fp16 K-frags
// (2MB) + V-frags (4MB) frag-major + y2/x2 row norms. Grid (NK/64, BB).
// [round-8 proven verbatim, minus b=0 mirrors]
// ---------------------------------------------------------------------------
__global__ __launch_bounds__(256)
void k0_prep(const float* __restrict__ Q, const float* __restrict__ Kp,
             const float* __restrict__ V, half8* __restrict__ Khg,
             half8* __restrict__ Vhg, float* __restrict__ y2g,
             float* __restrict__ x2g)
{
    __shared__ float sVt[64 * VV];       // 32 KB fp32 V tile

    const int t = threadIdx.x, b = blockIdx.y, tile = blockIdx.x;
    const int kt = tile * 64;
    const float* Kb = Kp + (size_t)b * NK * DD;
    const float* Qb = Q  + (size_t)b * NQ * DD;
    const float* Vb = V  + (size_t)b * NK * VV;

    // coalesced V tile load: 64 rows x 128 cols = 2048 float4
#pragma unroll
    for (int i = 0; i < 8; ++i)
        ((float4*)sVt)[t + i * 256] = ((const float4*)(Vb + (size_t)kt * VV))[t + i * 256];

    // K frags: 2/thread (identical mapping + cvt8 as prior rounds)
#pragma unroll
    for (int i = 0; i < 2; ++i) {
        int s = t + i * 256, f = s >> 6, l = s & 63;
        int krow = kt + (f >> 1) * 16 + (l & 15);
        int dcol = (f & 1) * 32 + (l >> 4) * 8;
        const float4* kp = (const float4*)(Kb + (size_t)krow * DD + dcol);
        Khg[khg_idx(b, tile, f, l)] = cvt8(kp[0], kp[1]);
    }
    // norms (same fmaf chain as prior rounds)
    if (t < 64) {
        const float4* kr = (const float4*)(Kb + (size_t)(kt + t) * DD);
        float s = 0.f;
#pragma unroll
        for (int i = 0; i < 16; ++i) {
            float4 v = kr[i];
            s = fmaf(v.x,v.x,s); s = fmaf(v.y,v.y,s);
            s = fmaf(v.z,v.z,s); s = fmaf(v.w,v.w,s);
        }
        y2g[(size_t)b * NK + kt + t] = s;
    } else if (t < 128) {
        int r = t - 64;
        const float4* qr = (const float4*)(Qb + (size_t)(kt + r) * DD);
        float s = 0.f;
#pragma unroll
        for (int i = 0; i < 16; ++i) {
            float4 v = qr[i];
            s = fmaf(v.x,v.x,s); s = fmaf(v.y,v.y,s);
            s = fmaf(v.z,v.z,s); s = fmaf(v.w,v.w,s);
        }
        x2g[(size_t)b * NQ + kt + r] = s;
    }
    __syncthreads();

    // V frags from LDS (same element values + cvt as the proven gather)
#pragma unroll
    for (int i = 0; i < 4; ++i) {
        int s = t + i * 256, f = s >> 6, l = s & 63;
        int krow_l = (f & 1) * 32 + (l >> 4) * 8;
        int vcol   = (f >> 1) * 16 + (l & 15);
        half8 h;
#pragma unroll
        for (int j = 0; j < 8; ++j) h[j] = (half_t)sVt[(krow_l + j) * VV + vcol];
        Vhg[vhg_idx(b, tile, f, l)] = h;
    }
}

// ---------------------------------------------------------------------------
// K_MAIN: 512 threads = 8 waves (qh = w&1 row-half, kq = w>>1 col-quarter).
// Two proven sweeps (round-8 verbatim), global-direct frags from d_ws,
// W always stored (no scratch in the W region anymore).
// Sweep 1: rowsum; wave (qh,kq) sweeps cols kq*512..+512 (8 tiles).
// Sweep 2: per tile, QK^T (2 MFMA) -> wv = e*rlr -> nt W store + fp16 sSh
//          -> PV (4 MFMA) -> O = acc directly.
// Grid: flat 512 blocks, XCD-swizzled so each XCD owns one batch b.
// ---------------------------------------------------------------------------
__global__ __launch_bounds__(512, 4)
void k_main(const float* __restrict__ Q, const half8* __restrict__ Khg,
            const half8* __restrict__ Vhg, const float* __restrict__ y2g,
            const float* __restrict__ x2g, float* __restrict__ W,
            float* __restrict__ O)
{
    __shared__ half_t sSh[32 * 64];      // 4 KB fp16 scores bounce (swizzled)
    __shared__ float  y2k[NK];           // 8 KB
    __shared__ float  part[4][32];
    __shared__ float  rsumS[32];

    const int t = threadIdx.x, w = t >> 6, lane = t & 63;
    const int n = lane & 15, quad = lane >> 4;
    const int qh = w & 1, kq = w >> 1;   // kq in 0..3

    // XCD swizzle: 512 blocks, 8 XCDs -> XCD i handles batch b=i entirely
    const int bid = blockIdx.x;
    const int swz = (bid & 7) * 64 + (bid >> 3);
    const int b = swz >> 6, qb = (swz & 63) * 32;

    const float* Qb = Q + (size_t)b * NQ * DD;

    // y2 full row set: 512 threads x 1 float4
    ((float4*)y2k)[t] = ((const float4*)(y2g + (size_t)b * NK))[t];

    half8 af[2];
#pragma unroll
    for (int ds = 0; ds < 2; ++ds) {
        const float4* qp = (const float4*)(Qb + (size_t)(qb + qh*16 + n) * DD + ds*32 + quad*8);
        af[ds] = cvt8(qp[0], qp[1]);
    }
    float x2r[4];
#pragma unroll
    for (int r = 0; r < 4; ++r)
        x2r[r] = x2g[(size_t)b * NQ + qb + qh * 16 + quad * 4 + r];
    __syncthreads();    // y2k ready

    // ============ sweep 1: row sums, barrier-free, global-direct K ==========
    float srow[4] = {0.f, 0.f, 0.f, 0.f};

    half8 bf[8];
#pragma unroll
    for (int f = 0; f < 8; ++f) bf[f] = Khg[khg_idx(b, kq * 8, f, lane)];

#pragma unroll 1
    for (int kt0 = 0; kt0 < 512; kt0 += 64) {
        const bool pf = (kt0 + 64) < 512;
        half8 bfn[8];
        if (pf) {
#pragma unroll
            for (int f = 0; f < 8; ++f)
                bfn[f] = Khg[khg_idx(b, kq * 8 + ((kt0 + 64) >> 6), f, lane)];
        }

        floatx4 acc4[4] = {};
#pragma unroll
        for (int nt = 0; nt < 4; ++nt)
#pragma unroll
            for (int ds = 0; ds < 2; ++ds)
                acc4[nt] = __builtin_amdgcn_mfma_f32_16x16x32_f16(
                    af[ds], bf[nt * 2 + ds], acc4[nt], 0, 0, 0);

#pragma unroll
        for (int nt = 0; nt < 4; ++nt) {
            int lcol = kq * 512 + kt0 + nt * 16 + n;
            float y2 = y2k[lcol];
#pragma unroll
            for (int r = 0; r < 4; ++r)
                srow[r] += score_exp(x2r[r], y2, acc4[nt][r]);
        }
        if (pf) {
#pragma unroll
            for (int f = 0; f < 8; ++f) bf[f] = bfn[f];
        }
    }

    // reduce over the 16 col-lanes (n), then over the 4 kq quarters
#pragma unroll
    for (int off = 1; off < 16; off <<= 1)
#pragma unroll
        for (int r = 0; r < 4; ++r) srow[r] += __shfl_xor(srow[r], off);
    if (n == 0)
#pragma unroll
        for (int r = 0; r < 4; ++r) part[kq][qh * 16 + quad * 4 + r] = srow[r];
    __syncthreads();
    if (t < 32)
        rsumS[t] = (part[0][t] + part[1][t]) + (part[2][t] + part[3][t]);
    __syncthreads();

    float rlr[4];
#pragma unroll
    for (int r = 0; r < 4; ++r)
        rlr[r] = __builtin_amdgcn_rcpf(rsumS[qh * 16 + quad * 4 + r]);

    // ============ sweep 2: scores -> W + sSh(fp16) -> PV, global-direct =====
    float* Wb = W + (size_t)b * NQ * NK;
    floatx4 acc[2] = {};

    half8 kf[2];
#pragma unroll
    for (int ds = 0; ds < 2; ++ds) kf[ds] = Khg[khg_idx(b, 0, kq * 2 + ds, lane)];

#pragma unroll 1
    for (int tt = 0; tt < NT3; ++tt) {
        const bool pf = (tt + 1) < NT3;

        // B) QK^T for cols kq*16..+15 (2 MFMAs over the d-halves)
        floatx4 a2 = {};
        a2 = __builtin_amdgcn_mfma_f32_16x16x32_f16(af[0], kf[0], a2, 0, 0, 0);
        a2 = __builtin_amdgcn_mfma_f32_16x16x32_f16(af[1], kf[1], a2, 0, 0, 0);

        // issue V-frags (this tile) + K-frags (next tile) early: L2 latency
        // hides under the score VALU phase below
        half8 vf[4];
        vf[0] = Vhg[vhg_idx(b, tt, kq * 2,           lane)];
        vf[1] = Vhg[vhg_idx(b, tt, kq * 2 + 1,       lane)];
        vf[2] = Vhg[vhg_idx(b, tt, (kq + 4) * 2,     lane)];
        vf[3] = Vhg[vhg_idx(b, tt, (kq + 4) * 2 + 1, lane)];
        half8 kfn[2];
        if (pf) {
#pragma unroll
            for (int ds = 0; ds < 2; ++ds)
                kfn[ds] = Khg[khg_idx(b, tt + 1, kq * 2 + ds, lane)];
        }

        // C) scores -> normalized W (nt store) + fp16 sSh
        {
            int col  = kq * 16 + n;
            int gcol = tt * 64 + col;
            float y2 = y2k[gcol];
#pragma unroll
            for (int r = 0; r < 4; ++r) {
                float e  = score_exp(x2r[r], y2, a2[r]);
                float wv = e * rlr[r];
                int row = qh * 16 + quad * 4 + r;
                __builtin_nontemporal_store(wv, Wb + (size_t)(qb + row) * NK + gcol);
                *(half_t*)((char*)sSh + ssh_byte(row, col)) = (half_t)wv;
            }
        }
        __syncthreads();   // sSh visible

        // D) PV: A-frags from sSh; v-colblocks kq and kq+4
        const int row2 = qh * 16 + n;
        half8 a0 = *(const half8*)((const char*)sSh + ssh_byte(row2, quad * 8));
        half8 a1 = *(const half8*)((const char*)sSh + ssh_byte(row2, 32 + quad * 8));
        acc[0] = __builtin_amdgcn_mfma_f32_16x16x32_f16(a0, vf[0], acc[0], 0, 0, 0);
        acc[0] = __builtin_amdgcn_mfma_f32_16x16x32_f16(a1, vf[1], acc[0], 0, 0, 0);
        acc[1] = __builtin_amdgcn_mfma_f32_16x16x32_f16(a0, vf[2], acc[1], 0, 0, 0);
        acc[1] = __builtin_amdgcn_mfma_f32_16x16x32_f16(a1, vf[3], acc[1], 0, 0, 0);
        __syncthreads();   // sSh reuse protected

        if (pf) { kf[0] = kfn[0]; kf[1] = kfn[1]; }
    }

    // A-frags were pre-normalized -> acc IS the output
    float* Ob = O + (size_t)b * NQ * VV;
#pragma unroll
    for (int ci = 0; ci < 2; ++ci) {
        int c = kq + ci * 4;
#pragma unroll
        for (int r = 0; r < 4; ++r)
            Ob[(size_t)(qb + qh * 16 + quad * 4 + r) * VV + c * 16 + n]
                = acc[ci][r];
    }
}

// ---------------------------------------------------------------------------
extern "C" void kernel_launch(void* const* d_in, const int* in_sizes, int n_in,
                              void* d_out, int out_size, void* d_ws, size_t ws_size,
                              hipStream_t stream)
{
    const float* Q  = (const float*)d_in[0];
    const float* Kp = (const float*)d_in[1];
    const float* Vp = (const float*)d_in[2];

    float* O     = (float*)d_out;                 // (B, Nq, V)
    float* attnW = O + (size_t)BB * NQ * VV;      // (B, Nq, Nk) normalized W

    // frag scratch in d_ws (round 9 proved ws_size >= 6.4 MB):
    //   Khg (2MB) | Vhg (4MB) | y2 (64KB) | x2 (64KB)
    half8* Khg = (half8*)d_ws;
    half8* Vhg = Khg + (size_t)BB * NT3 * 8 * 64;
    float* y2g = (float*)(Vhg + (size_t)BB * NT3 * 16 * 64);
    float* x2g = y2g + (size_t)BB * NK;

    k0_prep<<<dim3(NK / 64, BB),   256, 0, stream>>>(Q, Kp, Vp, Khg, Vhg, y2g, x2g);
    k_main <<<dim3(BB * (NQ / 32)), 512, 0, stream>>>(Q, Khg, Vhg, y2g, x2g, attnW, O);
}